// Round 1
// baseline (221.777 us; speedup 1.0000x reference)
//
#include <hip/hip_runtime.h>

#define GN 4096
#define KS 8          // split-K factor for A@h GEMM

typedef __attribute__((ext_vector_type(8))) short bf16x8_t;
typedef __attribute__((ext_vector_type(4))) float f32x4_t;

__device__ __forceinline__ short f2bf(float x) {
    union { float f; unsigned u; } c; c.f = x;
    unsigned r = (c.u + 0x7fffu + ((c.u >> 16) & 1u)) >> 16;   // RNE
    return (short)r;
}

// ---------------- encoder: h = relu(X @ Wenc^T + benc) -----------------
// writes h fp32 [4096][64] and Ht bf16 [64][4096] (transposed, k-contiguous)
__global__ __launch_bounds__(256) void encoder_k(
    const float* __restrict__ X, const float* __restrict__ Wenc,
    const float* __restrict__ benc, float* __restrict__ h,
    short* __restrict__ Ht)
{
    const int g = blockIdx.x * 256 + threadIdx.x;   // 0 .. 4096*64-1
    const int i = g >> 6, f = g & 63;
    const float4 x0 = *(const float4*)(X + i * 8);
    const float4 x1 = *(const float4*)(X + i * 8 + 4);
    const float4 w0 = *(const float4*)(Wenc + f * 8);
    const float4 w1 = *(const float4*)(Wenc + f * 8 + 4);
    float acc = benc[f]
              + x0.x * w0.x + x0.y * w0.y + x0.z * w0.z + x0.w * w0.w
              + x1.x * w1.x + x1.y * w1.y + x1.z * w1.z + x1.w * w1.w;
    acc = fmaxf(acc, 0.f);
    h[g] = acc;
    Ht[f * GN + i] = f2bf(acc);
}

// ---------------- GEMM: part[ks] += A[mt..mt+64][kseg] @ h[kseg][64] ----
// A fp32 row-major (converted to bf16 in-register), Ht bf16 [64][4096].
// grid (KS, 64), 256 threads (4 waves, 16 rows each), MFMA 16x16x32 bf16.
__global__ __launch_bounds__(256) void gemm_ah(
    const float* __restrict__ A, const short* __restrict__ Ht,
    float* __restrict__ part, int ks_len)
{
    __shared__ short Al[4 * 64 * 8];   // [quad][m][j]   4 KB
    __shared__ short Bl[4 * 64 * 8];   // [quad][n][j]   4 KB

    const int t  = threadIdx.x;
    const int ks = blockIdx.x;
    const int mt = blockIdx.y << 6;
    const int kb = ks * ks_len;

    const int row_ld = t >> 2;     // 0..63
    const int p_ld   = t & 3;      // 0..3  == quad of the 8-elem chunk

    const float* aP = A  + (size_t)(mt + row_ld) * GN + kb + p_ld * 8;
    const short* bP = Ht + row_ld * GN + kb + p_ld * 8;
    short* AlW = &Al[(p_ld * 64 + row_ld) * 8];
    short* BlW = &Bl[(p_ld * 64 + row_ld) * 8];

    const int w = t >> 6, lane = t & 63;
    const int quad = lane >> 4, l16 = lane & 15;
    const short* AlR = &Al[(quad * 64 + w * 16 + l16) * 8];
    const short* BlR = &Bl[(quad * 64 + l16) * 8];

    f32x4_t acc0 = {0.f, 0.f, 0.f, 0.f};
    f32x4_t acc1 = acc0, acc2 = acc0, acc3 = acc0;

    float4 a0 = *(const float4*)aP;
    float4 a1 = *(const float4*)(aP + 4);
    bf16x8_t bv = *(const bf16x8_t*)bP;

    for (int kk = 0; kk < ks_len; kk += 32) {
        bf16x8_t av;
        av[0] = f2bf(a0.x); av[1] = f2bf(a0.y);
        av[2] = f2bf(a0.z); av[3] = f2bf(a0.w);
        av[4] = f2bf(a1.x); av[5] = f2bf(a1.y);
        av[6] = f2bf(a1.z); av[7] = f2bf(a1.w);
        *(bf16x8_t*)AlW = av;
        *(bf16x8_t*)BlW = bv;
        __syncthreads();
        if (kk + 32 < ks_len) {              // prefetch next tile
            aP += 32; bP += 32;
            a0 = *(const float4*)aP;
            a1 = *(const float4*)(aP + 4);
            bv = *(const bf16x8_t*)bP;
        }
        bf16x8_t af = *(const bf16x8_t*)AlR;
        bf16x8_t b0 = *(const bf16x8_t*)(BlR);
        bf16x8_t b1 = *(const bf16x8_t*)(BlR + 16 * 8);
        bf16x8_t b2 = *(const bf16x8_t*)(BlR + 32 * 8);
        bf16x8_t b3 = *(const bf16x8_t*)(BlR + 48 * 8);
        acc0 = __builtin_amdgcn_mfma_f32_16x16x32_bf16(af, b0, acc0, 0, 0, 0);
        acc1 = __builtin_amdgcn_mfma_f32_16x16x32_bf16(af, b1, acc1, 0, 0, 0);
        acc2 = __builtin_amdgcn_mfma_f32_16x16x32_bf16(af, b2, acc2, 0, 0, 0);
        acc3 = __builtin_amdgcn_mfma_f32_16x16x32_bf16(af, b3, acc3, 0, 0, 0);
        __syncthreads();                     // reads done before next overwrite
    }

    // C/D layout: m = quad*4 + reg, n = nt*16 + l16
    float* o = part + ((size_t)ks * GN + mt + w * 16 + quad * 4) * 64 + l16;
    #pragma unroll
    for (int r = 0; r < 4; ++r) {
        o[r * 64 +  0] = acc0[r];
        o[r * 64 + 16] = acc1[r];
        o[r * 64 + 32] = acc2[r];
        o[r * 64 + 48] = acc3[r];
    }
}

// ---------------- dense: h = relu([h, sum_ks part] @ W^T + b) -----------
// last round: compute s_i = h@w_i, s_j = h@w_j instead of writing h/Ht.
__global__ __launch_bounds__(256) void dense_mlp(
    const float* __restrict__ hin, const float* __restrict__ part,
    const float* __restrict__ W, const float* __restrict__ bias,
    float* __restrict__ hout, short* __restrict__ HtOut,
    const float* __restrict__ Wedge,
    float* __restrict__ s_i, float* __restrict__ s_j, int last)
{
    __shared__ float hl[256];
    __shared__ float hnl[256];
    __shared__ float Wl[64 * 129];       // +1 pad -> conflict-free
    const int t = threadIdx.x;
    const int node0 = blockIdx.x * 4;

    {   // stage h and summed neighbor partials (4 nodes x 64 feats)
        const int iloc = t >> 6, k = t & 63;
        const size_t idx = (size_t)(node0 + iloc) * 64 + k;
        hl[t] = hin[idx];
        float s = 0.f;
        #pragma unroll
        for (int p = 0; p < KS; ++p) s += part[(size_t)p * GN * 64 + idx];
        hnl[t] = s;
    }
    {   // stage W (64x128) into padded LDS, coalesced float4 loads
        #pragma unroll
        for (int o = 0; o < 8; ++o) {
            const int g = t * 4 + o * 1024;
            const float4 v = *(const float4*)(W + g);
            const int r = g >> 7, c = g & 127;
            float* d = &Wl[r * 129 + c];
            d[0] = v.x; d[1] = v.y; d[2] = v.z; d[3] = v.w;
        }
    }
    __syncthreads();

    const int iloc = t >> 6, f = t & 63;
    const int node = node0 + iloc;
    float acc = bias[f];
    const float* wrow  = &Wl[f * 129];
    const float* hrow  = &hl[iloc * 64];
    const float* hnrow = &hnl[iloc * 64];
    #pragma unroll
    for (int k = 0; k < 64; ++k) acc += hrow[k] * wrow[k];
    #pragma unroll
    for (int k = 0; k < 64; ++k) acc += hnrow[k] * wrow[64 + k];
    acc = fmaxf(acc, 0.f);

    if (!last) {
        hout[(size_t)node * 64 + f] = acc;
        HtOut[f * GN + node] = f2bf(acc);
    } else {
        float vi = acc * Wedge[f];
        float vj = acc * Wedge[64 + f];
        #pragma unroll
        for (int off = 32; off > 0; off >>= 1) {
            vi += __shfl_xor(vi, off, 64);
            vj += __shfl_xor(vj, off, 64);
        }
        if (f == 0) { s_i[node] = vi; s_j[node] = vj; }
    }
}

// ---------------- scores: out[i][j] = s_i[i] + s_j[j] + be, diag 0 ------
__global__ __launch_bounds__(256) void scores_k(
    const float* __restrict__ s_i, const float* __restrict__ s_j,
    const float* __restrict__ be, float* __restrict__ out)
{
    const int i  = blockIdx.y;
    const int j0 = (blockIdx.x * 256 + threadIdx.x) * 4;
    const float si = s_i[i] + be[0];
    const float4 sj = *(const float4*)(s_j + j0);
    float4 o = make_float4(si + sj.x, si + sj.y, si + sj.z, si + sj.w);
    const int d = i - j0;
    if (d >= 0 && d < 4) (&o.x)[d] = 0.f;
    *(float4*)(out + (size_t)i * GN + j0) = o;
}

extern "C" void kernel_launch(void* const* d_in, const int* in_sizes, int n_in,
                              void* d_out, int out_size, void* d_ws, size_t ws_size,
                              hipStream_t stream) {
    const float* X     = (const float*)d_in[0];
    const float* A     = (const float*)d_in[1];
    const float* Wenc  = (const float*)d_in[2];
    const float* benc  = (const float*)d_in[3];
    const float* Wmat[3] = {(const float*)d_in[4], (const float*)d_in[6], (const float*)d_in[8]};
    const float* bvec[3] = {(const float*)d_in[5], (const float*)d_in[7], (const float*)d_in[9]};
    const float* Wedge = (const float*)d_in[10];
    const float* bedge = (const float*)d_in[11];
    float* out = (float*)d_out;

    char* ws = (char*)d_ws;
    float* part = (float*)ws;                                   // KS*4096*64 f32 = 8 MiB
    float* h    = (float*)(ws + ((size_t)8 << 20));             // 1 MiB
    short* Ht   = (short*)(ws + ((size_t)9 << 20));             // 0.5 MiB
    float* s_i  = (float*)(ws + ((size_t)9 << 20) + (512u << 10));
    float* s_j  = s_i + GN;

    encoder_k<<<dim3(GN * 64 / 256), 256, 0, stream>>>(X, Wenc, benc, h, Ht);

    for (int r = 0; r < 3; ++r) {
        gemm_ah<<<dim3(KS, GN / 64), 256, 0, stream>>>(A, Ht, part, GN / KS);
        dense_mlp<<<dim3(GN / 4), 256, 0, stream>>>(
            h, part, Wmat[r], bvec[r], h, Ht, Wedge, s_i, s_j, r == 2);
    }

    scores_k<<<dim3(GN / 1024, GN), 256, 0, stream>>>(s_i, s_j, bedge, out);
}